// Round 1
// baseline (448.445 us; speedup 1.0000x reference)
//
#include <hip/hip_runtime.h>
#include <hip/hip_bf16.h>

// Problem constants
#define B_ 4
#define S_ 2048
#define D_ 1024
#define H_ 16
#define DH_ 64

using f32x4  = __attribute__((ext_vector_type(4))) float;
using bf16x8 = __attribute__((ext_vector_type(8))) __bf16;

__device__ __forceinline__ unsigned short f2bf(float f) {
    union { float f; unsigned int u; } x; x.f = f;
    unsigned int r = (x.u + 0x7FFFu + ((x.u >> 16) & 1u)) >> 16;  // RNE
    return (unsigned short)r;
}

// ---------------- fp32 -> bf16 convert (weights) ----------------
__global__ __launch_bounds__(256) void cvt_f32_bf16(const float* __restrict__ in,
                                                    unsigned short* __restrict__ out, int n) {
    int i = (blockIdx.x * 256 + threadIdx.x) * 4;
    if (i + 3 < n) {
        float4 v = *(const float4*)&in[i];
        ushort4 h;
        h.x = f2bf(v.x); h.y = f2bf(v.y); h.z = f2bf(v.z); h.w = f2bf(v.w);
        *(ushort4*)&out[i] = h;
    }
}

// ---------------- GEMM: C = A @ W^T + bias ----------------
// A: [M,K] (fp32 if AF32 else bf16), W: [N,K] bf16 row-major.
// OMODE 0: write bf16 into [B,H,S,DH] proj layout. OMODE 1: write fp32 row-major.
template<bool AF32, int OMODE>
__global__ __launch_bounds__(256) void gemm_bt(const void* __restrict__ Ap,
                                               const unsigned short* __restrict__ Bw,
                                               const float* __restrict__ bias,
                                               void* __restrict__ Cp,
                                               int M, int N, int K)
{
    constexpr int BM = 128, BN = 128, BK = 32, LDK = 40;  // +8 pad -> 2-way conflicts only
    __shared__ unsigned short As[BM][LDK];
    __shared__ unsigned short Bs[BN][LDK];

    const int tid  = threadIdx.x;
    const int lane = tid & 63, wid = tid >> 6;
    const int row0 = blockIdx.x * BM, col0 = blockIdx.y * BN;
    const int wm = (wid >> 1) * 64, wn = (wid & 1) * 64;
    const int fr = lane & 15, fg = lane >> 4;

    f32x4 acc[4][4] = {};

    const int ar = tid >> 1;         // 0..127 staging row
    const int ac = (tid & 1) * 16;   // 0/16 staging col base

    for (int k0 = 0; k0 < K; k0 += BK) {
        if (AF32) {
            const float* A = (const float*)Ap;
            #pragma unroll
            for (int j = 0; j < 4; ++j) {
                float4 v = *(const float4*)&A[(size_t)(row0 + ar) * K + k0 + ac + 4 * j];
                ushort4 h;
                h.x = f2bf(v.x); h.y = f2bf(v.y); h.z = f2bf(v.z); h.w = f2bf(v.w);
                *(ushort4*)&As[ar][ac + 4 * j] = h;
            }
        } else {
            const unsigned short* A = (const unsigned short*)Ap;
            #pragma unroll
            for (int j = 0; j < 2; ++j) {
                int4 v = *(const int4*)&A[(size_t)(row0 + ar) * K + k0 + ac + 8 * j];
                *(int4*)&As[ar][ac + 8 * j] = v;
            }
        }
        #pragma unroll
        for (int j = 0; j < 2; ++j) {
            int4 v = *(const int4*)&Bw[(size_t)(col0 + ar) * K + k0 + ac + 8 * j];
            *(int4*)&Bs[ar][ac + 8 * j] = v;
        }
        __syncthreads();

        bf16x8 af[4], bf[4];
        #pragma unroll
        for (int i = 0; i < 4; ++i) af[i] = *(const bf16x8*)&As[wm + i * 16 + fr][8 * fg];
        #pragma unroll
        for (int i = 0; i < 4; ++i) bf[i] = *(const bf16x8*)&Bs[wn + i * 16 + fr][8 * fg];
        #pragma unroll
        for (int i = 0; i < 4; ++i)
            #pragma unroll
            for (int j = 0; j < 4; ++j)
                acc[i][j] = __builtin_amdgcn_mfma_f32_16x16x32_bf16(af[i], bf[j], acc[i][j], 0, 0, 0);
        __syncthreads();
    }

    // Epilogue. Verified C/D layout: col = lane&15, row = (lane>>4)*4 + reg.
    #pragma unroll
    for (int i = 0; i < 4; ++i) {
        #pragma unroll
        for (int j = 0; j < 4; ++j) {
            int col = col0 + wn + j * 16 + fr;
            float bv = bias[col];
            #pragma unroll
            for (int r = 0; r < 4; ++r) {
                int row = row0 + wm + i * 16 + fg * 4 + r;
                float val = acc[i][j][r] + bv;
                if (OMODE == 0) {
                    // proj layout [B,H,S,DH]: m=b*S+s, n=h*64+dh
                    unsigned short* Cb = (unsigned short*)Cp;
                    int b = row >> 11, s = row & 2047, h = col >> 6, dh = col & 63;
                    Cb[((((b << 4) + h) * 2048 + s) << 6) + dh] = f2bf(val);
                } else {
                    float* Cf = (float*)Cp;
                    Cf[(size_t)row * N + col] = val;
                }
            }
        }
    }
}

// ---------------- Flash attention (causal), bf16 MFMA ----------------
// grid: (S/64, B*H). block 256 = 4 waves, each wave owns 16 q-rows.
// Quirk folded in: softmax((QK^T + mask*(-1e9))/32) == causal mask, scale 1/32.
__global__ __launch_bounds__(256) void attn_fwd(const unsigned short* __restrict__ Qp,
                                                const unsigned short* __restrict__ Kp,
                                                const unsigned short* __restrict__ Vp,
                                                unsigned short* __restrict__ ctx)
{
    constexpr float SC = 0.045084221670f;  // log2(e)/32
    __shared__ unsigned short Ks[64][72];     // K tile [kv][dh], +8 pad
    __shared__ unsigned short Vt[64][72];     // V^T tile [dh][kv]
    __shared__ unsigned short Ps[4][16][72];  // per-wave P [qrow][kv]

    const int qb = blockIdx.x;
    const int bh = blockIdx.y;
    const int b = bh >> 4, h = bh & 15;
    const int tid = threadIdx.x, lane = tid & 63, wid = tid >> 6;
    const int fr = lane & 15, fg = lane >> 4;

    const unsigned short* Qh = Qp + (size_t)bh * (S_ * DH_);
    const unsigned short* Kh = Kp + (size_t)bh * (S_ * DH_);
    const unsigned short* Vh = Vp + (size_t)bh * (S_ * DH_);

    const int q0 = qb * 64;

    // Q fragments hoisted to registers (16x64 per wave -> 2 A-frags)
    bf16x8 qf[2];
    const int qrow = q0 + wid * 16 + fr;
    #pragma unroll
    for (int ks = 0; ks < 2; ++ks)
        qf[ks] = *(const bf16x8*)&Qh[qrow * 64 + ks * 32 + 8 * fg];

    f32x4 oacc[4] = {};
    float m_run[4], l_run[4];
    #pragma unroll
    for (int r = 0; r < 4; ++r) { m_run[r] = -3.0e38f; l_run[r] = 0.0f; }

    const int sr = tid & 63;  // staging row (lane) -> 2-way-free LDS writes

    for (int kt = 0; kt <= qb; ++kt) {
        const int kv0 = kt * 64;
        // stage K (vectorized) and V^T (scalar transpose writes)
        #pragma unroll
        for (int j = 0; j < 2; ++j) {
            int c = ((tid >> 6) + 4 * j) * 8;
            int4 kv = *(const int4*)&Kh[(size_t)(kv0 + sr) * 64 + c];
            *(int4*)&Ks[sr][c] = kv;
            int4 vv = *(const int4*)&Vh[(size_t)(kv0 + sr) * 64 + c];
            const unsigned short* vs = (const unsigned short*)&vv;
            #pragma unroll
            for (int e = 0; e < 8; ++e) Vt[c + e][sr] = vs[e];
        }
        __syncthreads();

        // S = Q @ K^T : 16x64 per wave
        f32x4 sacc[4] = {};
        #pragma unroll
        for (int nt = 0; nt < 4; ++nt) {
            #pragma unroll
            for (int ks = 0; ks < 2; ++ks) {
                bf16x8 kf = *(const bf16x8*)&Ks[nt * 16 + fr][ks * 32 + 8 * fg];
                sacc[nt] = __builtin_amdgcn_mfma_f32_16x16x32_bf16(qf[ks], kf, sacc[nt], 0, 0, 0);
            }
        }

        // causal mask on diagonal tile
        if (kt == qb) {
            #pragma unroll
            for (int nt = 0; nt < 4; ++nt) {
                int colg = kv0 + nt * 16 + fr;
                #pragma unroll
                for (int r = 0; r < 4; ++r) {
                    int rowg = q0 + wid * 16 + fg * 4 + r;
                    if (colg > rowg) sacc[nt][r] = -3.0e38f;
                }
            }
        }

        // online softmax (rows live across the 16 lanes of each lane-group)
        float alpha[4], rs[4];
        #pragma unroll
        for (int r = 0; r < 4; ++r) {
            float v = fmaxf(fmaxf(sacc[0][r], sacc[1][r]), fmaxf(sacc[2][r], sacc[3][r]));
            v = fmaxf(v, __shfl_xor(v, 1));
            v = fmaxf(v, __shfl_xor(v, 2));
            v = fmaxf(v, __shfl_xor(v, 4));
            v = fmaxf(v, __shfl_xor(v, 8));
            float mn = fmaxf(m_run[r], v);
            alpha[r] = exp2f((m_run[r] - mn) * SC);
            m_run[r] = mn;
            rs[r] = 0.0f;
        }
        #pragma unroll
        for (int nt = 0; nt < 4; ++nt)
            #pragma unroll
            for (int r = 0; r < 4; ++r) {
                float p = exp2f((sacc[nt][r] - m_run[r]) * SC);
                sacc[nt][r] = p;
                rs[r] += p;
            }
        #pragma unroll
        for (int r = 0; r < 4; ++r) {
            float v = rs[r];
            v += __shfl_xor(v, 1); v += __shfl_xor(v, 2);
            v += __shfl_xor(v, 4); v += __shfl_xor(v, 8);
            l_run[r] = l_run[r] * alpha[r] + v;
        }
        #pragma unroll
        for (int dt = 0; dt < 4; ++dt)
            #pragma unroll
            for (int r = 0; r < 4; ++r) oacc[dt][r] *= alpha[r];

        // P -> LDS (bf16), re-read as PV A-fragments (wave-private region)
        #pragma unroll
        for (int nt = 0; nt < 4; ++nt)
            #pragma unroll
            for (int r = 0; r < 4; ++r)
                Ps[wid][fg * 4 + r][nt * 16 + fr] = f2bf(sacc[nt][r]);
        asm volatile("s_waitcnt lgkmcnt(0)" ::: "memory");

        bf16x8 pa[2];
        #pragma unroll
        for (int ks = 0; ks < 2; ++ks)
            pa[ks] = *(const bf16x8*)&Ps[wid][fr][ks * 32 + 8 * fg];
        #pragma unroll
        for (int dt = 0; dt < 4; ++dt) {
            #pragma unroll
            for (int ks = 0; ks < 2; ++ks) {
                bf16x8 vf = *(const bf16x8*)&Vt[dt * 16 + fr][ks * 32 + 8 * fg];
                oacc[dt] = __builtin_amdgcn_mfma_f32_16x16x32_bf16(pa[ks], vf, oacc[dt], 0, 0, 0);
            }
        }
        __syncthreads();
    }

    // epilogue: ctx[b][s][h*64+dh] (standard [B,S,D] bf16)
    #pragma unroll
    for (int dt = 0; dt < 4; ++dt) {
        int dh = dt * 16 + fr;
        #pragma unroll
        for (int r = 0; r < 4; ++r) {
            int s = q0 + wid * 16 + fg * 4 + r;
            float v = oacc[dt][r] / l_run[r];
            ctx[(size_t)(b * 2048 + s) * 1024 + h * 64 + dh] = f2bf(v);
        }
    }
}

extern "C" void kernel_launch(void* const* d_in, const int* in_sizes, int n_in,
                              void* d_out, int out_size, void* d_ws, size_t ws_size,
                              hipStream_t stream)
{
    const float* q  = (const float*)d_in[0];
    const float* k  = (const float*)d_in[1];
    const float* v  = (const float*)d_in[2];
    // d_in[3] = mask: causal triu by construction -> folded into attn kernel
    const float* Wq = (const float*)d_in[4];
    const float* bq = (const float*)d_in[5];
    const float* Wk = (const float*)d_in[6];
    const float* bk = (const float*)d_in[7];
    const float* Wv = (const float*)d_in[8];
    const float* bv = (const float*)d_in[9];
    const float* Wo = (const float*)d_in[10];
    const float* bo = (const float*)d_in[11];
    float* out = (float*)d_out;

    // ws layout (75.5 MB total)
    unsigned short* Wqb = (unsigned short*)d_ws;
    unsigned short* Wkb = Wqb + 1024 * 1024;
    unsigned short* Wvb = Wkb + 1024 * 1024;
    unsigned short* Wob = Wvb + 1024 * 1024;
    unsigned short* Qp  = Wob + 1024 * 1024;
    unsigned short* Kp  = Qp + 8192 * 1024;
    unsigned short* Vp  = Kp + 8192 * 1024;
    unsigned short* Ctx = Vp + 8192 * 1024;

    dim3 blk(256);
    cvt_f32_bf16<<<dim3(1024), blk, 0, stream>>>(Wq, Wqb, 1024 * 1024);
    cvt_f32_bf16<<<dim3(1024), blk, 0, stream>>>(Wk, Wkb, 1024 * 1024);
    cvt_f32_bf16<<<dim3(1024), blk, 0, stream>>>(Wv, Wvb, 1024 * 1024);
    cvt_f32_bf16<<<dim3(1024), blk, 0, stream>>>(Wo, Wob, 1024 * 1024);

    dim3 g1(64, 8);
    gemm_bt<true, 0><<<g1, blk, 0, stream>>>(q, Wqb, bq, Qp, 8192, 1024, 1024);
    gemm_bt<true, 0><<<g1, blk, 0, stream>>>(k, Wkb, bk, Kp, 8192, 1024, 1024);
    gemm_bt<true, 0><<<g1, blk, 0, stream>>>(v, Wvb, bv, Vp, 8192, 1024, 1024);

    attn_fwd<<<dim3(32, 64), blk, 0, stream>>>(Qp, Kp, Vp, Ctx);

    gemm_bt<false, 1><<<g1, blk, 0, stream>>>(Ctx, Wob, bo, out, 8192, 1024, 1024);
}

// Round 2
// 342.491 us; speedup vs baseline: 1.3094x; 1.3094x over previous
//
#include <hip/hip_runtime.h>
#include <hip/hip_bf16.h>

#define B_ 4
#define S_ 2048
#define D_ 1024
#define H_ 16
#define DH_ 64

using f32x4  = __attribute__((ext_vector_type(4))) float;
using bf16x8 = __attribute__((ext_vector_type(8))) __bf16;
typedef unsigned short ushort_t;

__device__ __forceinline__ unsigned short f2bf(float f) {
    union { float f; unsigned int u; } x; x.f = f;
    unsigned int r = (x.u + 0x7FFFu + ((x.u >> 16) & 1u)) >> 16;  // RNE
    return (unsigned short)r;
}

// ---------------- fp32 -> bf16 convert (weights) ----------------
__global__ __launch_bounds__(256) void cvt_f32_bf16(const float* __restrict__ in,
                                                    unsigned short* __restrict__ out, int n) {
    int i = (blockIdx.x * 256 + threadIdx.x) * 4;
    if (i + 3 < n) {
        float4 v = *(const float4*)&in[i];
        ushort4 h;
        h.x = f2bf(v.x); h.y = f2bf(v.y); h.z = f2bf(v.z); h.w = f2bf(v.w);
        *(ushort4*)&out[i] = h;
    }
}

// ---------------- GEMM: C = A @ W^T + bias ----------------
// A: [M,K] (fp32 if AF32 else bf16), W: [N,K] bf16 row-major.
// OMODE 0: bf16 into [B,H,S,DH]. OMODE 1: fp32 row-major. OMODE 2: bf16 into [B,H,DH,S] (V^T).
template<bool AF32, int OMODE>
__global__ __launch_bounds__(256) void gemm_bt(const void* __restrict__ Ap,
                                               const unsigned short* __restrict__ Bw,
                                               const float* __restrict__ bias,
                                               void* __restrict__ Cp,
                                               int M, int N, int K)
{
    constexpr int BM = 128, BN = 128, BK = 32, LDK = 40;
    __shared__ unsigned short As[BM][LDK];
    __shared__ unsigned short Bs[BN][LDK];

    const int tid  = threadIdx.x;
    const int lane = tid & 63, wid = tid >> 6;
    const int row0 = blockIdx.x * BM, col0 = blockIdx.y * BN;
    const int wm = (wid >> 1) * 64, wn = (wid & 1) * 64;
    const int fr = lane & 15, fg = lane >> 4;

    f32x4 acc[4][4] = {};

    const int ar = tid >> 1;
    const int ac = (tid & 1) * 16;

    for (int k0 = 0; k0 < K; k0 += BK) {
        if (AF32) {
            const float* A = (const float*)Ap;
            #pragma unroll
            for (int j = 0; j < 4; ++j) {
                float4 v = *(const float4*)&A[(size_t)(row0 + ar) * K + k0 + ac + 4 * j];
                ushort4 h;
                h.x = f2bf(v.x); h.y = f2bf(v.y); h.z = f2bf(v.z); h.w = f2bf(v.w);
                *(ushort4*)&As[ar][ac + 4 * j] = h;
            }
        } else {
            const unsigned short* A = (const unsigned short*)Ap;
            #pragma unroll
            for (int j = 0; j < 2; ++j) {
                int4 v = *(const int4*)&A[(size_t)(row0 + ar) * K + k0 + ac + 8 * j];
                *(int4*)&As[ar][ac + 8 * j] = v;
            }
        }
        #pragma unroll
        for (int j = 0; j < 2; ++j) {
            int4 v = *(const int4*)&Bw[(size_t)(col0 + ar) * K + k0 + ac + 8 * j];
            *(int4*)&Bs[ar][ac + 8 * j] = v;
        }
        __syncthreads();

        bf16x8 af[4], bfr[4];
        #pragma unroll
        for (int i = 0; i < 4; ++i) af[i] = *(const bf16x8*)&As[wm + i * 16 + fr][8 * fg];
        #pragma unroll
        for (int i = 0; i < 4; ++i) bfr[i] = *(const bf16x8*)&Bs[wn + i * 16 + fr][8 * fg];
        #pragma unroll
        for (int i = 0; i < 4; ++i)
            #pragma unroll
            for (int j = 0; j < 4; ++j)
                acc[i][j] = __builtin_amdgcn_mfma_f32_16x16x32_bf16(af[i], bfr[j], acc[i][j], 0, 0, 0);
        __syncthreads();
    }

    #pragma unroll
    for (int i = 0; i < 4; ++i) {
        #pragma unroll
        for (int j = 0; j < 4; ++j) {
            int col = col0 + wn + j * 16 + fr;
            float bv = bias[col];
            #pragma unroll
            for (int r = 0; r < 4; ++r) {
                int row = row0 + wm + i * 16 + fg * 4 + r;
                float val = acc[i][j][r] + bv;
                if (OMODE == 0) {
                    unsigned short* Cb = (unsigned short*)Cp;
                    int b = row >> 11, s = row & 2047, h = col >> 6, dh = col & 63;
                    Cb[((((b << 4) + h) * 2048 + s) << 6) + dh] = f2bf(val);
                } else if (OMODE == 2) {
                    unsigned short* Cb = (unsigned short*)Cp;
                    int b = row >> 11, s = row & 2047, h = col >> 6, dh = col & 63;
                    Cb[((size_t)((b << 4) + h) * 64 + dh) * 2048 + s] = f2bf(val);
                } else {
                    float* Cf = (float*)Cp;
                    Cf[(size_t)row * N + col] = val;
                }
            }
        }
    }
}

// ---------------- Flash attention v2 ----------------
// Block: 4 waves x 32 q-rows = 128 q-rows. Processes the q-block pair (j, 15-j)
// -> exactly 34 KV-tile iterations per block. Grid (8, 64) = 512 blocks = 2/CU.
// V comes pre-transposed in [B,H,DH,S] (VTg). P round-trips through wave-private LDS.
__global__ __launch_bounds__(256) void attn_fwd2(const unsigned short* __restrict__ Qp,
                                                 const unsigned short* __restrict__ Kp,
                                                 const unsigned short* __restrict__ VTg,
                                                 unsigned short* __restrict__ ctx)
{
    constexpr float SC = 0.0450842200277f;  // log2(e)/sqrt(1024)
    __shared__ unsigned short Ks[64][68];      // [kv][dh], +4 pad
    __shared__ unsigned short Vt[64][68];      // [dh][kv], +4 pad
    __shared__ unsigned short Ps[4][32][68];   // per-wave P [qrow][kv]

    const int pi = blockIdx.x;  // pair index 0..7
    const int bh = blockIdx.y;
    const int b = bh >> 4, h = bh & 15;
    const int tid = threadIdx.x, lane = tid & 63, wid = tid >> 6;
    const int fr = lane & 15, fg = lane >> 4;

    const unsigned short* Qh  = Qp  + (size_t)bh * (S_ * DH_);
    const unsigned short* Kh  = Kp  + (size_t)bh * (S_ * DH_);
    const unsigned short* VTh = VTg + (size_t)bh * (DH_ * S_);

    const int srow = tid >> 2;         // staging row 0..63
    const int scol = (tid & 3) * 16;   // staging col base

    for (int half = 0; half < 2; ++half) {
        const int j = half ? (15 - pi) : pi;
        const int q0 = j * 128;
        const int ntiles = 2 * (j + 1);

        // Q fragments (wave-private, in registers)
        bf16x8 qf[2][2];
        #pragma unroll
        for (int m = 0; m < 2; ++m) {
            int qrow = q0 + wid * 32 + m * 16 + fr;
            #pragma unroll
            for (int ks = 0; ks < 2; ++ks)
                qf[m][ks] = *(const bf16x8*)&Qh[qrow * 64 + ks * 32 + 8 * fg];
        }

        f32x4 oacc[2][4] = {};
        float m_run[2][4], l_run[2][4];
        #pragma unroll
        for (int m = 0; m < 2; ++m)
            #pragma unroll
            for (int r = 0; r < 4; ++r) { m_run[m][r] = -3.0e38f; l_run[m][r] = 0.0f; }

        // prefetch tile 0 into regs
        int4 kreg[2], vreg[2];
        #pragma unroll
        for (int u = 0; u < 2; ++u) {
            kreg[u] = *(const int4*)&Kh[(size_t)srow * 64 + scol + 8 * u];
            vreg[u] = *(const int4*)&VTh[(size_t)srow * 2048 + scol + 8 * u];
        }

        for (int kt = 0; kt < ntiles; ++kt) {
            const int kv0 = kt * 64;
            __syncthreads();  // previous compute's LDS reads done
            #pragma unroll
            for (int u = 0; u < 2; ++u) {
                *(int4*)&Ks[srow][scol + 8 * u] = kreg[u];
                *(int4*)&Vt[srow][scol + 8 * u] = vreg[u];
            }
            if (kt + 1 < ntiles) {
                const int kv1 = kv0 + 64;
                #pragma unroll
                for (int u = 0; u < 2; ++u) {
                    kreg[u] = *(const int4*)&Kh[(size_t)(kv1 + srow) * 64 + scol + 8 * u];
                    vreg[u] = *(const int4*)&VTh[(size_t)srow * 2048 + kv1 + scol + 8 * u];
                }
            }
            __syncthreads();  // tile staged

            // S = Q @ K^T  (two 16-row subtiles share kf)
            f32x4 sacc[2][4] = {};
            #pragma unroll
            for (int nt = 0; nt < 4; ++nt) {
                #pragma unroll
                for (int ks = 0; ks < 2; ++ks) {
                    bf16x8 kf = *(const bf16x8*)&Ks[nt * 16 + fr][ks * 32 + 8 * fg];
                    sacc[0][nt] = __builtin_amdgcn_mfma_f32_16x16x32_bf16(qf[0][ks], kf, sacc[0][nt], 0, 0, 0);
                    sacc[1][nt] = __builtin_amdgcn_mfma_f32_16x16x32_bf16(qf[1][ks], kf, sacc[1][nt], 0, 0, 0);
                }
            }

            // causal mask (only when the KV tile can cross the diagonal)
            #pragma unroll
            for (int m = 0; m < 2; ++m) {
                const int rbase = q0 + wid * 32 + m * 16;
                if (kv0 + 63 > rbase) {
                    #pragma unroll
                    for (int nt = 0; nt < 4; ++nt) {
                        int colg = kv0 + nt * 16 + fr;
                        #pragma unroll
                        for (int r = 0; r < 4; ++r)
                            if (colg > rbase + fg * 4 + r) sacc[m][nt][r] = -3.0e38f;
                    }
                }
            }

            // online softmax — 8 independent reduce chains (2m x 4r) interleave
            float vmax[2][4], alpha[2][4], rs[2][4];
            #pragma unroll
            for (int m = 0; m < 2; ++m)
                #pragma unroll
                for (int r = 0; r < 4; ++r)
                    vmax[m][r] = fmaxf(fmaxf(sacc[m][0][r], sacc[m][1][r]),
                                       fmaxf(sacc[m][2][r], sacc[m][3][r]));
            #pragma unroll
            for (int st = 1; st <= 8; st <<= 1)
                #pragma unroll
                for (int m = 0; m < 2; ++m)
                    #pragma unroll
                    for (int r = 0; r < 4; ++r)
                        vmax[m][r] = fmaxf(vmax[m][r], __shfl_xor(vmax[m][r], st));
            #pragma unroll
            for (int m = 0; m < 2; ++m)
                #pragma unroll
                for (int r = 0; r < 4; ++r) {
                    float mn = fmaxf(m_run[m][r], vmax[m][r]);
                    alpha[m][r] = exp2f((m_run[m][r] - mn) * SC);
                    m_run[m][r] = mn;
                    rs[m][r] = 0.0f;
                }
            #pragma unroll
            for (int m = 0; m < 2; ++m)
                #pragma unroll
                for (int nt = 0; nt < 4; ++nt)
                    #pragma unroll
                    for (int r = 0; r < 4; ++r) {
                        float p = exp2f((sacc[m][nt][r] - m_run[m][r]) * SC);
                        sacc[m][nt][r] = p;
                        rs[m][r] += p;
                    }
            #pragma unroll
            for (int st = 1; st <= 8; st <<= 1)
                #pragma unroll
                for (int m = 0; m < 2; ++m)
                    #pragma unroll
                    for (int r = 0; r < 4; ++r)
                        rs[m][r] += __shfl_xor(rs[m][r], st);
            #pragma unroll
            for (int m = 0; m < 2; ++m)
                #pragma unroll
                for (int r = 0; r < 4; ++r)
                    l_run[m][r] = l_run[m][r] * alpha[m][r] + rs[m][r];
            #pragma unroll
            for (int m = 0; m < 2; ++m)
                #pragma unroll
                for (int dt = 0; dt < 4; ++dt)
                    #pragma unroll
                    for (int r = 0; r < 4; ++r)
                        oacc[m][dt][r] *= alpha[m][r];

            // P -> wave-private LDS (bf16)
            #pragma unroll
            for (int m = 0; m < 2; ++m)
                #pragma unroll
                for (int nt = 0; nt < 4; ++nt)
                    #pragma unroll
                    for (int r = 0; r < 4; ++r)
                        Ps[wid][m * 16 + fg * 4 + r][nt * 16 + fr] = f2bf(sacc[m][nt][r]);
            asm volatile("s_waitcnt lgkmcnt(0)" ::: "memory");

            bf16x8 pa[2][2];
            #pragma unroll
            for (int m = 0; m < 2; ++m)
                #pragma unroll
                for (int ks = 0; ks < 2; ++ks)
                    pa[m][ks] = *(const bf16x8*)&Ps[wid][m * 16 + fr][ks * 32 + 8 * fg];

            #pragma unroll
            for (int dt = 0; dt < 4; ++dt) {
                #pragma unroll
                for (int ks = 0; ks < 2; ++ks) {
                    bf16x8 vf = *(const bf16x8*)&Vt[dt * 16 + fr][ks * 32 + 8 * fg];
                    oacc[0][dt] = __builtin_amdgcn_mfma_f32_16x16x32_bf16(pa[0][ks], vf, oacc[0][dt], 0, 0, 0);
                    oacc[1][dt] = __builtin_amdgcn_mfma_f32_16x16x32_bf16(pa[1][ks], vf, oacc[1][dt], 0, 0, 0);
                }
            }
        }

        // epilogue for this q-block
        #pragma unroll
        for (int m = 0; m < 2; ++m)
            #pragma unroll
            for (int dt = 0; dt < 4; ++dt) {
                int dh = dt * 16 + fr;
                #pragma unroll
                for (int r = 0; r < 4; ++r) {
                    int s = q0 + wid * 32 + m * 16 + fg * 4 + r;
                    float v = oacc[m][dt][r] / l_run[m][r];
                    ctx[(size_t)(b * 2048 + s) * 1024 + h * 64 + dh] = f2bf(v);
                }
            }
    }
}

extern "C" void kernel_launch(void* const* d_in, const int* in_sizes, int n_in,
                              void* d_out, int out_size, void* d_ws, size_t ws_size,
                              hipStream_t stream)
{
    const float* q  = (const float*)d_in[0];
    const float* k  = (const float*)d_in[1];
    const float* v  = (const float*)d_in[2];
    const float* Wq = (const float*)d_in[4];
    const float* bq = (const float*)d_in[5];
    const float* Wk = (const float*)d_in[6];
    const float* bk = (const float*)d_in[7];
    const float* Wv = (const float*)d_in[8];
    const float* bv = (const float*)d_in[9];
    const float* Wo = (const float*)d_in[10];
    const float* bo = (const float*)d_in[11];
    float* out = (float*)d_out;

    unsigned short* Wqb = (unsigned short*)d_ws;
    unsigned short* Wkb = Wqb + 1024 * 1024;
    unsigned short* Wvb = Wkb + 1024 * 1024;
    unsigned short* Wob = Wvb + 1024 * 1024;
    unsigned short* Qp  = Wob + 1024 * 1024;
    unsigned short* Kp  = Qp + 8192 * 1024;
    unsigned short* VTp = Kp + 8192 * 1024;   // V in [B,H,DH,S]
    unsigned short* Ctx = VTp + 8192 * 1024;

    dim3 blk(256);
    cvt_f32_bf16<<<dim3(1024), blk, 0, stream>>>(Wq, Wqb, 1024 * 1024);
    cvt_f32_bf16<<<dim3(1024), blk, 0, stream>>>(Wk, Wkb, 1024 * 1024);
    cvt_f32_bf16<<<dim3(1024), blk, 0, stream>>>(Wv, Wvb, 1024 * 1024);
    cvt_f32_bf16<<<dim3(1024), blk, 0, stream>>>(Wo, Wob, 1024 * 1024);

    dim3 g1(64, 8);
    gemm_bt<true, 0><<<g1, blk, 0, stream>>>(q, Wqb, bq, Qp, 8192, 1024, 1024);
    gemm_bt<true, 0><<<g1, blk, 0, stream>>>(k, Wkb, bk, Kp, 8192, 1024, 1024);
    gemm_bt<true, 2><<<g1, blk, 0, stream>>>(v, Wvb, bv, VTp, 8192, 1024, 1024);

    attn_fwd2<<<dim3(8, 64), blk, 0, stream>>>(Qp, Kp, VTp, Ctx);

    gemm_bt<false, 1><<<g1, blk, 0, stream>>>(Ctx, Wob, bo, out, 8192, 1024, 1024);
}

// Round 3
// 272.134 us; speedup vs baseline: 1.6479x; 1.2585x over previous
//
#include <hip/hip_runtime.h>
#include <hip/hip_bf16.h>

#define B_ 4
#define S_ 2048
#define D_ 1024
#define H_ 16
#define DH_ 64

using f32x4  = __attribute__((ext_vector_type(4))) float;
using bf16x8 = __attribute__((ext_vector_type(8))) __bf16;

__device__ __forceinline__ unsigned short f2bf(float f) {
    union { float f; unsigned int u; } x; x.f = f;
    unsigned int r = (x.u + 0x7FFFu + ((x.u >> 16) & 1u)) >> 16;  // RNE
    return (unsigned short)r;
}

// ---------------- fp32 -> bf16 convert (weights) ----------------
__global__ __launch_bounds__(256) void cvt_f32_bf16(const float* __restrict__ in,
                                                    unsigned short* __restrict__ out, int n) {
    int i = (blockIdx.x * 256 + threadIdx.x) * 4;
    if (i + 3 < n) {
        float4 v = *(const float4*)&in[i];
        ushort4 h;
        h.x = f2bf(v.x); h.y = f2bf(v.y); h.z = f2bf(v.z); h.w = f2bf(v.w);
        *(ushort4*)&out[i] = h;
    }
}

// ---------------- GEMM: C = (A @ W^T + bias) * oscale ----------------
// A: [M,K] (fp32 if AF32 else bf16), W: [N,K] bf16 row-major.
// OMODE 0: bf16 into [B,H,S,DH]. OMODE 1: fp32 row-major. OMODE 2: bf16 into [B,H,DH,S] (V^T).
template<bool AF32, int OMODE>
__global__ __launch_bounds__(256) void gemm_bt(const void* __restrict__ Ap,
                                               const unsigned short* __restrict__ Bw,
                                               const float* __restrict__ bias,
                                               void* __restrict__ Cp,
                                               int M, int N, int K, float oscale)
{
    constexpr int BM = 128, BN = 128, BK = 32, LDK = 40;
    __shared__ unsigned short As[BM][LDK];
    __shared__ unsigned short Bs[BN][LDK];

    const int tid  = threadIdx.x;
    const int lane = tid & 63, wid = tid >> 6;
    const int row0 = blockIdx.x * BM, col0 = blockIdx.y * BN;
    const int wm = (wid >> 1) * 64, wn = (wid & 1) * 64;
    const int fr = lane & 15, fg = lane >> 4;

    f32x4 acc[4][4] = {};

    const int ar = tid >> 1;
    const int ac = (tid & 1) * 16;

    for (int k0 = 0; k0 < K; k0 += BK) {
        if (AF32) {
            const float* A = (const float*)Ap;
            #pragma unroll
            for (int j = 0; j < 4; ++j) {
                float4 v = *(const float4*)&A[(size_t)(row0 + ar) * K + k0 + ac + 4 * j];
                ushort4 h;
                h.x = f2bf(v.x); h.y = f2bf(v.y); h.z = f2bf(v.z); h.w = f2bf(v.w);
                *(ushort4*)&As[ar][ac + 4 * j] = h;
            }
        } else {
            const unsigned short* A = (const unsigned short*)Ap;
            #pragma unroll
            for (int j = 0; j < 2; ++j) {
                int4 v = *(const int4*)&A[(size_t)(row0 + ar) * K + k0 + ac + 8 * j];
                *(int4*)&As[ar][ac + 8 * j] = v;
            }
        }
        #pragma unroll
        for (int j = 0; j < 2; ++j) {
            int4 v = *(const int4*)&Bw[(size_t)(col0 + ar) * K + k0 + ac + 8 * j];
            *(int4*)&Bs[ar][ac + 8 * j] = v;
        }
        __syncthreads();

        bf16x8 af[4], bfr[4];
        #pragma unroll
        for (int i = 0; i < 4; ++i) af[i] = *(const bf16x8*)&As[wm + i * 16 + fr][8 * fg];
        #pragma unroll
        for (int i = 0; i < 4; ++i) bfr[i] = *(const bf16x8*)&Bs[wn + i * 16 + fr][8 * fg];
        #pragma unroll
        for (int i = 0; i < 4; ++i)
            #pragma unroll
            for (int j = 0; j < 4; ++j)
                acc[i][j] = __builtin_amdgcn_mfma_f32_16x16x32_bf16(af[i], bfr[j], acc[i][j], 0, 0, 0);
        __syncthreads();
    }

    #pragma unroll
    for (int i = 0; i < 4; ++i) {
        #pragma unroll
        for (int j = 0; j < 4; ++j) {
            int col = col0 + wn + j * 16 + fr;
            float bv = bias[col];
            #pragma unroll
            for (int r = 0; r < 4; ++r) {
                int row = row0 + wm + i * 16 + fg * 4 + r;
                float val = (acc[i][j][r] + bv) * oscale;
                if (OMODE == 0) {
                    unsigned short* Cb = (unsigned short*)Cp;
                    int b = row >> 11, s = row & 2047, h = col >> 6, dh = col & 63;
                    Cb[((((b << 4) + h) * 2048 + s) << 6) + dh] = f2bf(val);
                } else if (OMODE == 2) {
                    unsigned short* Cb = (unsigned short*)Cp;
                    int b = row >> 11, s = row & 2047, h = col >> 6, dh = col & 63;
                    Cb[((size_t)((b << 4) + h) * 64 + dh) * 2048 + s] = f2bf(val);
                } else {
                    float* Cf = (float*)Cp;
                    Cf[(size_t)row * N + col] = val;
                }
            }
        }
    }
}

// ---------------- Flash attention v3 ----------------
// 512 threads = 8 waves x 16 q-rows = 128-row q-tile. Pair (j, 15-j) -> 34 KV
// iters/block. Grid 512 flat, XCD-swizzled so each XCD owns 8 complete heads
// (K/V working set 4MB = one L2). Q pre-scaled by log2(e)/32 in its GEMM.
// Row-sum of P computed by MFMA against a ones-fragment (no sum shuffles).
__global__ __launch_bounds__(512, 4) void attn_fwd3(const unsigned short* __restrict__ Qp,
                                                    const unsigned short* __restrict__ Kp,
                                                    const unsigned short* __restrict__ VTg,
                                                    unsigned short* __restrict__ ctx)
{
    __shared__ unsigned short Ks[64][68];      // [kv][dh]
    __shared__ unsigned short Vt[64][68];      // [dh][kv]
    __shared__ unsigned short Ps[8][16][68];   // per-wave P [qrow][kv]

    const int lin = blockIdx.x;
    const int bh = (lin & 7) * 8 + (lin >> 6);   // XCD (lin%8) owns heads 8x..8x+7
    const int pi = (lin >> 3) & 7;
    const int b = bh >> 4, h = bh & 15;
    const int tid = threadIdx.x, lane = tid & 63, wid = tid >> 6;
    const int fr = lane & 15, fg = lane >> 4;

    const unsigned short* Qh  = Qp  + (size_t)bh * (S_ * DH_);
    const unsigned short* Kh  = Kp  + (size_t)bh * (S_ * DH_);
    const unsigned short* VTh = VTg + (size_t)bh * (DH_ * S_);

    const int srow = tid >> 3;         // 0..63
    const int scol = (tid & 7) * 8;    // 0..56

    bf16x8 ones;
    #pragma unroll
    for (int i = 0; i < 8; ++i) ones[i] = (__bf16)1.0f;

    for (int half = 0; half < 2; ++half) {
        const int j = half ? (15 - pi) : pi;
        const int q0 = j * 128;
        const int ntiles = 2 * (j + 1);
        const int rbase = q0 + wid * 16;

        bf16x8 qf[2];
        #pragma unroll
        for (int ks = 0; ks < 2; ++ks)
            qf[ks] = *(const bf16x8*)&Qh[(rbase + fr) * 64 + ks * 32 + 8 * fg];

        f32x4 oacc[4] = {};
        float m_run[4], l_run[4];
        #pragma unroll
        for (int r = 0; r < 4; ++r) { m_run[r] = -3.0e38f; l_run[r] = 0.0f; }

        int4 kreg = *(const int4*)&Kh[(size_t)srow * 64 + scol];
        int4 vreg = *(const int4*)&VTh[(size_t)srow * 2048 + scol];

        for (int kt = 0; kt < ntiles; ++kt) {
            const int kv0 = kt * 64;
            __syncthreads();
            *(int4*)&Ks[srow][scol] = kreg;
            *(int4*)&Vt[srow][scol] = vreg;
            if (kt + 1 < ntiles) {
                const int kv1 = kv0 + 64;
                kreg = *(const int4*)&Kh[(size_t)(kv1 + srow) * 64 + scol];
                vreg = *(const int4*)&VTh[(size_t)srow * 2048 + kv1 + scol];
            }
            __syncthreads();

            if (kv0 > rbase + 15) continue;  // fully masked for this wave

            // S = Q @ K^T  (Q pre-scaled: sacc is in exp2 units)
            f32x4 sacc[4] = {};
            #pragma unroll
            for (int nt = 0; nt < 4; ++nt)
                #pragma unroll
                for (int ks = 0; ks < 2; ++ks) {
                    bf16x8 kf = *(const bf16x8*)&Ks[nt * 16 + fr][ks * 32 + 8 * fg];
                    sacc[nt] = __builtin_amdgcn_mfma_f32_16x16x32_bf16(qf[ks], kf, sacc[nt], 0, 0, 0);
                }

            if (kv0 + 63 > rbase) {
                #pragma unroll
                for (int nt = 0; nt < 4; ++nt) {
                    int colg = kv0 + nt * 16 + fr;
                    #pragma unroll
                    for (int r = 0; r < 4; ++r)
                        if (colg > rbase + fg * 4 + r) sacc[nt][r] = -3.0e38f;
                }
            }

            // row max (across 16 fr-lanes), then alpha
            float vmax[4], alpha[4];
            #pragma unroll
            for (int r = 0; r < 4; ++r)
                vmax[r] = fmaxf(fmaxf(sacc[0][r], sacc[1][r]), fmaxf(sacc[2][r], sacc[3][r]));
            #pragma unroll
            for (int st = 1; st <= 8; st <<= 1)
                #pragma unroll
                for (int r = 0; r < 4; ++r)
                    vmax[r] = fmaxf(vmax[r], __shfl_xor(vmax[r], st));
            #pragma unroll
            for (int r = 0; r < 4; ++r) {
                float mn = fmaxf(m_run[r], vmax[r]);
                alpha[r] = exp2f(m_run[r] - mn);
                m_run[r] = mn;
            }

            // P = exp2(S - m) -> wave-private LDS
            #pragma unroll
            for (int nt = 0; nt < 4; ++nt)
                #pragma unroll
                for (int r = 0; r < 4; ++r)
                    Ps[wid][fg * 4 + r][nt * 16 + fr] = f2bf(exp2f(sacc[nt][r] - m_run[r]));

            #pragma unroll
            for (int dt = 0; dt < 4; ++dt)
                #pragma unroll
                for (int r = 0; r < 4; ++r) oacc[dt][r] *= alpha[r];

            asm volatile("s_waitcnt lgkmcnt(0)" ::: "memory");

            bf16x8 pa[2];
            #pragma unroll
            for (int ks = 0; ks < 2; ++ks)
                pa[ks] = *(const bf16x8*)&Ps[wid][fr][ks * 32 + 8 * fg];

            f32x4 racc = {};
            #pragma unroll
            for (int ks = 0; ks < 2; ++ks)
                racc = __builtin_amdgcn_mfma_f32_16x16x32_bf16(pa[ks], ones, racc, 0, 0, 0);
            #pragma unroll
            for (int dt = 0; dt < 4; ++dt)
                #pragma unroll
                for (int ks = 0; ks < 2; ++ks) {
                    bf16x8 vf = *(const bf16x8*)&Vt[dt * 16 + fr][ks * 32 + 8 * fg];
                    oacc[dt] = __builtin_amdgcn_mfma_f32_16x16x32_bf16(pa[ks], vf, oacc[dt], 0, 0, 0);
                }
            #pragma unroll
            for (int r = 0; r < 4; ++r)
                l_run[r] = l_run[r] * alpha[r] + racc[r];
        }

        #pragma unroll
        for (int r = 0; r < 4; ++r) l_run[r] = 1.0f / l_run[r];
        #pragma unroll
        for (int dt = 0; dt < 4; ++dt) {
            int dh = dt * 16 + fr;
            #pragma unroll
            for (int r = 0; r < 4; ++r) {
                int s = rbase + fg * 4 + r;
                ctx[(size_t)(b * 2048 + s) * 1024 + h * 64 + dh] = f2bf(oacc[dt][r] * l_run[r]);
            }
        }
    }
}

extern "C" void kernel_launch(void* const* d_in, const int* in_sizes, int n_in,
                              void* d_out, int out_size, void* d_ws, size_t ws_size,
                              hipStream_t stream)
{
    const float* q  = (const float*)d_in[0];
    const float* k  = (const float*)d_in[1];
    const float* v  = (const float*)d_in[2];
    const float* Wq = (const float*)d_in[4];
    const float* bq = (const float*)d_in[5];
    const float* Wk = (const float*)d_in[6];
    const float* bk = (const float*)d_in[7];
    const float* Wv = (const float*)d_in[8];
    const float* bv = (const float*)d_in[9];
    const float* Wo = (const float*)d_in[10];
    const float* bo = (const float*)d_in[11];
    float* out = (float*)d_out;

    unsigned short* Wqb = (unsigned short*)d_ws;
    unsigned short* Wkb = Wqb + 1024 * 1024;
    unsigned short* Wvb = Wkb + 1024 * 1024;
    unsigned short* Wob = Wvb + 1024 * 1024;
    unsigned short* Qp  = Wob + 1024 * 1024;
    unsigned short* Kp  = Qp + 8192 * 1024;
    unsigned short* VTp = Kp + 8192 * 1024;   // V in [B,H,DH,S]
    unsigned short* Ctx = VTp + 8192 * 1024;

    // log2(e) / sqrt(D): folds the softmax scale into Q so exp2 is direct
    const float SCQ = 0.045084220027780106f;

    dim3 blk(256);
    cvt_f32_bf16<<<dim3(1024), blk, 0, stream>>>(Wq, Wqb, 1024 * 1024);
    cvt_f32_bf16<<<dim3(1024), blk, 0, stream>>>(Wk, Wkb, 1024 * 1024);
    cvt_f32_bf16<<<dim3(1024), blk, 0, stream>>>(Wv, Wvb, 1024 * 1024);
    cvt_f32_bf16<<<dim3(1024), blk, 0, stream>>>(Wo, Wob, 1024 * 1024);

    dim3 g1(64, 8);
    gemm_bt<true, 0><<<g1, blk, 0, stream>>>(q, Wqb, bq, Qp, 8192, 1024, 1024, SCQ);
    gemm_bt<true, 0><<<g1, blk, 0, stream>>>(k, Wkb, bk, Kp, 8192, 1024, 1024, 1.0f);
    gemm_bt<true, 2><<<g1, blk, 0, stream>>>(v, Wvb, bv, VTp, 8192, 1024, 1024, 1.0f);

    attn_fwd3<<<dim3(512), dim3(512), 0, stream>>>(Qp, Kp, VTp, Ctx);

    gemm_bt<false, 1><<<g1, blk, 0, stream>>>(Ctx, Wob, bo, out, 8192, 1024, 1024, 1.0f);
}

// Round 4
// 248.663 us; speedup vs baseline: 1.8034x; 1.0944x over previous
//
#include <hip/hip_runtime.h>
#include <hip/hip_bf16.h>

#define B_ 4
#define S_ 2048
#define D_ 1024
#define H_ 16
#define DH_ 64

using f32x4  = __attribute__((ext_vector_type(4))) float;
using bf16x8 = __attribute__((ext_vector_type(8))) __bf16;

__device__ __forceinline__ unsigned int f2bf(float f) {
    union { float f; unsigned int u; } x; x.f = f;
    return (x.u + 0x7FFFu + ((x.u >> 16) & 1u)) >> 16;  // RNE
}

// async global->LDS, 16B per lane. LDS dest must be wave-uniform base + lane*16.
__device__ __forceinline__ void gl_lds16(const unsigned short* g, unsigned short* l) {
    __builtin_amdgcn_global_load_lds(
        (const __attribute__((address_space(1))) unsigned int*)(const void*)g,
        (__attribute__((address_space(3))) unsigned int*)(void*)l,
        16, 0, 0);
}

// ---------------- fp32 -> bf16 bulk convert ----------------
__global__ __launch_bounds__(256) void cvt_f32_bf16(const float* __restrict__ in,
                                                    unsigned short* __restrict__ out, int n) {
    int i = (blockIdx.x * 256 + threadIdx.x) * 4;
    if (i + 3 < n) {
        float4 v = *(const float4*)&in[i];
        ushort4 h;
        h.x = f2bf(v.x); h.y = f2bf(v.y); h.z = f2bf(v.z); h.w = f2bf(v.w);
        *(ushort4*)&out[i] = h;
    }
}

// ---------------- GEMM (m97 structure): C = (A @ W^T + bias) * oscale ----------------
// A: [M,K] bf16, W: [N,K] bf16. 128x128 tile, BK=32, 4 waves, global_load_lds staging.
// OMODE 0: bf16 -> [B,H,S,DH]. OMODE 1: fp32 row-major. OMODE 2: bf16 -> [B,H,DH,S].
template<int OMODE>
__global__ __launch_bounds__(256) void gemm_bt2(const unsigned short* __restrict__ A,
                                                const unsigned short* __restrict__ Bw,
                                                const float* __restrict__ bias,
                                                void* __restrict__ Cp,
                                                int M, int N, int K, float oscale)
{
    constexpr int BM = 128, BN = 128, BK = 32;
    __shared__ unsigned short As[BM * BK];   // linear [128][32] (global_load_lds: no pad)
    __shared__ unsigned short Bs[BN * BK];

    const int tid  = threadIdx.x;
    const int lane = tid & 63, wid = tid >> 6;
    const int row0 = blockIdx.x * BM, col0 = blockIdx.y * BN;
    const int wm = (wid >> 1) * 64, wn = (wid & 1) * 64;
    const int fr = lane & 15, fg = lane >> 4;

    f32x4 acc[4][4] = {};

    // staging map: instr i covers LDS bytes [wid*1024 + i*4096, +1024); lane -> +lane*16
    const int srow = wid * 16 + (lane >> 2);   // + i*64
    const int scol = (lane & 3) * 8;           // elements
    const size_t abase = (size_t)(row0 + srow) * K + scol;
    const size_t bbase = (size_t)(col0 + srow) * K + scol;
    unsigned short* lA0 = &As[srow * BK + scol];
    unsigned short* lA1 = &As[(srow + 64) * BK + scol];
    unsigned short* lB0 = &Bs[srow * BK + scol];
    unsigned short* lB1 = &Bs[(srow + 64) * BK + scol];

    for (int k0 = 0; k0 < K; k0 += BK) {
        gl_lds16(&A[abase + k0], lA0);
        gl_lds16(&A[abase + (size_t)64 * K + k0], lA1);
        gl_lds16(&Bw[bbase + k0], lB0);
        gl_lds16(&Bw[bbase + (size_t)64 * K + k0], lB1);
        __syncthreads();  // drains vmcnt(0): tile resident

        bf16x8 af[4], bfr[4];
        #pragma unroll
        for (int i = 0; i < 4; ++i) af[i] = *(const bf16x8*)&As[(wm + i * 16 + fr) * BK + fg * 8];
        #pragma unroll
        for (int i = 0; i < 4; ++i) bfr[i] = *(const bf16x8*)&Bs[(wn + i * 16 + fr) * BK + fg * 8];
        #pragma unroll
        for (int i = 0; i < 4; ++i)
            #pragma unroll
            for (int j = 0; j < 4; ++j)
                acc[i][j] = __builtin_amdgcn_mfma_f32_16x16x32_bf16(af[i], bfr[j], acc[i][j], 0, 0, 0);
        __syncthreads();  // readers done before next stage
    }

    #pragma unroll
    for (int i = 0; i < 4; ++i) {
        #pragma unroll
        for (int j = 0; j < 4; ++j) {
            int col = col0 + wn + j * 16 + fr;
            float bv = bias[col];
            if (OMODE == 2) {
                // [B,H,DH,S]: consecutive r -> consecutive s: pack b64
                int row = row0 + wm + i * 16 + fg * 4;
                int b = row >> 11, s = row & 2047, h = col >> 6, dh = col & 63;
                unsigned int w0 = f2bf((acc[i][j][0] + bv) * oscale) |
                                  (f2bf((acc[i][j][1] + bv) * oscale) << 16);
                unsigned int w1 = f2bf((acc[i][j][2] + bv) * oscale) |
                                  (f2bf((acc[i][j][3] + bv) * oscale) << 16);
                unsigned short* Cb = (unsigned short*)Cp;
                *(uint2*)&Cb[((size_t)((b << 4) + h) * 64 + dh) * 2048 + s] = make_uint2(w0, w1);
            } else {
                #pragma unroll
                for (int r = 0; r < 4; ++r) {
                    int row = row0 + wm + i * 16 + fg * 4 + r;
                    float val = (acc[i][j][r] + bv) * oscale;
                    if (OMODE == 0) {
                        unsigned short* Cb = (unsigned short*)Cp;
                        int b = row >> 11, s = row & 2047, h = col >> 6, dh = col & 63;
                        Cb[((((b << 4) + h) * 2048 + s) << 6) + dh] = (unsigned short)f2bf(val);
                    } else {
                        float* Cf = (float*)Cp;
                        Cf[(size_t)row * N + col] = val;
                    }
                }
            }
        }
    }
}

// ---------------- Flash attention v4: swapped QK^T, S^T in registers ----------------
// 512 thr = 8 waves x 16 q-rows. Pair (j,15-j) -> 34 KV iters. XCD-swizzled grid.
// S^T = mfma(K,Q): lane owns q-col fr, kv rows (nt*16+fg*4+r). Softmax in-lane:
// 15 fmax + 2 shfl. P packed b64 to wave-private LDS -> B-frags for O^T = mfma(V^T, P).
__global__ __launch_bounds__(512, 4) void attn_fwd4(const unsigned short* __restrict__ Qp,
                                                    const unsigned short* __restrict__ Kp,
                                                    const unsigned short* __restrict__ VTg,
                                                    unsigned short* __restrict__ ctx)
{
    __shared__ unsigned short Ks[64][68];
    __shared__ unsigned short Vt[64][68];
    __shared__ unsigned short Ps[8][16][68];

    const int lin = blockIdx.x;
    const int bh = (lin & 7) * 8 + (lin >> 6);   // XCD (lin%8) owns heads 8x..8x+7
    const int pi = (lin >> 3) & 7;
    const int b = bh >> 4, h = bh & 15;
    const int tid = threadIdx.x, lane = tid & 63, wid = tid >> 6;
    const int fr = lane & 15, fg = lane >> 4;

    const unsigned short* Qh  = Qp  + (size_t)bh * (S_ * DH_);
    const unsigned short* Kh  = Kp  + (size_t)bh * (S_ * DH_);
    const unsigned short* VTh = VTg + (size_t)bh * (DH_ * S_);

    const int srow = tid >> 3;
    const int scol = (tid & 7) * 8;

    bf16x8 ones;
    #pragma unroll
    for (int i = 0; i < 8; ++i) ones[i] = (__bf16)1.0f;

    for (int half = 0; half < 2; ++half) {
        const int j = half ? (15 - pi) : pi;
        const int q0 = j * 128;
        const int ntiles = 2 * (j + 1);
        const int rbase = q0 + wid * 16;
        const int qg = rbase + fr;      // this lane's q row (global)

        bf16x8 qf[2];   // B-frag: lane holds Q-row rbase+fr
        #pragma unroll
        for (int ks = 0; ks < 2; ++ks)
            qf[ks] = *(const bf16x8*)&Qh[(size_t)qg * 64 + ks * 32 + 8 * fg];

        f32x4 oacc[4] = {};               // O^T: col q=fr, rows dh
        float m_run = -3.0e38f, l_run = 0.0f;

        int4 kreg = *(const int4*)&Kh[(size_t)srow * 64 + scol];
        int4 vreg = *(const int4*)&VTh[(size_t)srow * 2048 + scol];

        for (int kt = 0; kt < ntiles; ++kt) {
            const int kv0 = kt * 64;
            __syncthreads();
            *(int4*)&Ks[srow][scol] = kreg;
            *(int4*)&Vt[srow][scol] = vreg;
            if (kt + 1 < ntiles) {
                const int kv1 = kv0 + 64;
                kreg = *(const int4*)&Kh[(size_t)(kv1 + srow) * 64 + scol];
                vreg = *(const int4*)&VTh[(size_t)srow * 2048 + kv1 + scol];
            }
            __syncthreads();

            if (kv0 > rbase + 15) continue;  // wave fully masked for this tile

            // S^T = K @ Q^T : lane (fr,fg) reg r of tile nt = S[q=rbase+fr][kv0+nt*16+fg*4+r]
            f32x4 sacc[4] = {};
            #pragma unroll
            for (int nt = 0; nt < 4; ++nt)
                #pragma unroll
                for (int ks = 0; ks < 2; ++ks) {
                    bf16x8 kf = *(const bf16x8*)&Ks[nt * 16 + fr][ks * 32 + 8 * fg];
                    sacc[nt] = __builtin_amdgcn_mfma_f32_16x16x32_bf16(kf, qf[ks], sacc[nt], 0, 0, 0);
                }

            if (kv0 + 63 > rbase) {
                const int kbase = kv0 + fg * 4;
                #pragma unroll
                for (int nt = 0; nt < 4; ++nt)
                    #pragma unroll
                    for (int r = 0; r < 4; ++r)
                        if (kbase + nt * 16 + r > qg) sacc[nt][r] = -3.0e38f;
            }

            // row max: 15 in-lane fmax + 2 shuffles (across fg groups)
            float vm = sacc[0][0];
            #pragma unroll
            for (int nt = 0; nt < 4; ++nt)
                #pragma unroll
                for (int r = 0; r < 4; ++r) vm = fmaxf(vm, sacc[nt][r]);
            vm = fmaxf(vm, __shfl_xor(vm, 16));
            vm = fmaxf(vm, __shfl_xor(vm, 32));

            const float mn = fmaxf(m_run, vm);
            const float alpha = exp2f(m_run - mn);
            m_run = mn;

            // P = exp2(S - m), pack pairs, 4x b64 wave-private LDS writes
            #pragma unroll
            for (int nt = 0; nt < 4; ++nt) {
                unsigned int w0 = f2bf(exp2f(sacc[nt][0] - mn)) |
                                  (f2bf(exp2f(sacc[nt][1] - mn)) << 16);
                unsigned int w1 = f2bf(exp2f(sacc[nt][2] - mn)) |
                                  (f2bf(exp2f(sacc[nt][3] - mn)) << 16);
                *(uint2*)&Ps[wid][fr][nt * 16 + fg * 4] = make_uint2(w0, w1);
            }

            #pragma unroll
            for (int dt = 0; dt < 4; ++dt)
                #pragma unroll
                for (int r = 0; r < 4; ++r) oacc[dt][r] *= alpha;

            asm volatile("s_waitcnt lgkmcnt(0)" ::: "memory");

            // B-frag: lane holds P-row q=fr, kv ks*32+8fg..+7
            bf16x8 pb[2];
            #pragma unroll
            for (int ks = 0; ks < 2; ++ks)
                pb[ks] = *(const bf16x8*)&Ps[wid][fr][ks * 32 + 8 * fg];

            f32x4 racc = {};
            #pragma unroll
            for (int ks = 0; ks < 2; ++ks)
                racc = __builtin_amdgcn_mfma_f32_16x16x32_bf16(ones, pb[ks], racc, 0, 0, 0);
            #pragma unroll
            for (int dt = 0; dt < 4; ++dt)
                #pragma unroll
                for (int ks = 0; ks < 2; ++ks) {
                    bf16x8 vf = *(const bf16x8*)&Vt[dt * 16 + fr][ks * 32 + 8 * fg];
                    oacc[dt] = __builtin_amdgcn_mfma_f32_16x16x32_bf16(vf, pb[ks], oacc[dt], 0, 0, 0);
                }
            l_run = l_run * alpha + racc[0];
        }

        // epilogue: lane's q = one s-row; 4 packed b64 stores
        const float linv = 1.0f / l_run;
        unsigned short* cb = &ctx[(size_t)(b * 2048 + qg) * 1024 + h * 64];
        #pragma unroll
        for (int dt = 0; dt < 4; ++dt) {
            unsigned int w0 = f2bf(oacc[dt][0] * linv) | (f2bf(oacc[dt][1] * linv) << 16);
            unsigned int w1 = f2bf(oacc[dt][2] * linv) | (f2bf(oacc[dt][3] * linv) << 16);
            *(uint2*)&cb[dt * 16 + fg * 4] = make_uint2(w0, w1);
        }
    }
}

extern "C" void kernel_launch(void* const* d_in, const int* in_sizes, int n_in,
                              void* d_out, int out_size, void* d_ws, size_t ws_size,
                              hipStream_t stream)
{
    const float* q  = (const float*)d_in[0];
    const float* k  = (const float*)d_in[1];
    const float* v  = (const float*)d_in[2];
    const float* Wq = (const float*)d_in[4];
    const float* bq = (const float*)d_in[5];
    const float* Wk = (const float*)d_in[6];
    const float* bk = (const float*)d_in[7];
    const float* Wv = (const float*)d_in[8];
    const float* bv = (const float*)d_in[9];
    const float* Wo = (const float*)d_in[10];
    const float* bo = (const float*)d_in[11];
    float* out = (float*)d_out;

    const int NE = 8192 * 1024;  // elems per activation tensor
    unsigned short* Wqb = (unsigned short*)d_ws;
    unsigned short* Wkb = Wqb + 1024 * 1024;
    unsigned short* Wvb = Wkb + 1024 * 1024;
    unsigned short* Wob = Wvb + 1024 * 1024;
    unsigned short* qb  = Wob + 1024 * 1024;
    unsigned short* kb  = qb + NE;
    unsigned short* vb  = kb + NE;
    unsigned short* Qp  = vb + NE;
    unsigned short* Kp  = Qp + NE;
    unsigned short* VTp = Kp + NE;   // V in [B,H,DH,S]
    unsigned short* Ctx = VTp + NE;

    const float SCQ = 0.045084220027780106f;  // log2(e)/sqrt(D)

    dim3 blk(256);
    cvt_f32_bf16<<<dim3(1024), blk, 0, stream>>>(Wq, Wqb, 1024 * 1024);
    cvt_f32_bf16<<<dim3(1024), blk, 0, stream>>>(Wk, Wkb, 1024 * 1024);
    cvt_f32_bf16<<<dim3(1024), blk, 0, stream>>>(Wv, Wvb, 1024 * 1024);
    cvt_f32_bf16<<<dim3(1024), blk, 0, stream>>>(Wo, Wob, 1024 * 1024);
    cvt_f32_bf16<<<dim3(8192), blk, 0, stream>>>(q, qb, NE);
    cvt_f32_bf16<<<dim3(8192), blk, 0, stream>>>(k, kb, NE);
    cvt_f32_bf16<<<dim3(8192), blk, 0, stream>>>(v, vb, NE);

    dim3 g1(64, 8);
    gemm_bt2<0><<<g1, blk, 0, stream>>>(qb, Wqb, bq, Qp, 8192, 1024, 1024, SCQ);
    gemm_bt2<0><<<g1, blk, 0, stream>>>(kb, Wkb, bk, Kp, 8192, 1024, 1024, 1.0f);
    gemm_bt2<2><<<g1, blk, 0, stream>>>(vb, Wvb, bv, VTp, 8192, 1024, 1024, 1.0f);

    attn_fwd4<<<dim3(512), dim3(512), 0, stream>>>(Qp, Kp, VTp, Ctx);

    gemm_bt2<1><<<g1, blk, 0, stream>>>(Ctx, Wob, bo, out, 8192, 1024, 1024, 1.0f);
}

// Round 5
// 202.983 us; speedup vs baseline: 2.2093x; 1.2250x over previous
//
#include <hip/hip_runtime.h>
#include <hip/hip_bf16.h>

#define S_ 2048
#define DH_ 64
#define NE_ 8388608  // 8192*1024 elems per activation tensor

using f32x4  = __attribute__((ext_vector_type(4))) float;
using bf16x8 = __attribute__((ext_vector_type(8))) __bf16;
using bf16x4 = __attribute__((ext_vector_type(4))) __bf16;

__device__ __forceinline__ unsigned int f2bf(float f) {
    union { float f; unsigned int u; } x; x.f = f;
    return (x.u + 0x7FFFu + ((x.u >> 16) & 1u)) >> 16;  // RNE
}

// async global->LDS, 16B per lane. LDS dest = wave-uniform base + lane*16.
__device__ __forceinline__ void gl_lds16(const unsigned short* g, unsigned short* l) {
    __builtin_amdgcn_global_load_lds(
        (const __attribute__((address_space(1))) unsigned int*)(const void*)g,
        (__attribute__((address_space(3))) unsigned int*)(void*)l,
        16, 0, 0);
}

// ---------------- weight cvt: 4 x [1024,1024] fp32 -> bf16, concat ----------------
__global__ __launch_bounds__(256) void cvt_w4(const float* __restrict__ w0, const float* __restrict__ w1,
                                              const float* __restrict__ w2, const float* __restrict__ w3,
                                              unsigned short* __restrict__ out) {
    const float* src = blockIdx.y == 0 ? w0 : blockIdx.y == 1 ? w1 : blockIdx.y == 2 ? w2 : w3;
    unsigned short* dst = out + (size_t)blockIdx.y * 1048576;
    int i = (blockIdx.x * 256 + threadIdx.x) * 4;
    float4 v = *(const float4*)&src[i];
    ushort4 h;
    h.x = f2bf(v.x); h.y = f2bf(v.y); h.z = f2bf(v.z); h.w = f2bf(v.w);
    *(ushort4*)&dst[i] = h;
}

// ---------------- activation cvt: q,k,v fp32 -> bf16, concat ----------------
__global__ __launch_bounds__(256) void cvt_a3(const float* __restrict__ a0, const float* __restrict__ a1,
                                              const float* __restrict__ a2, unsigned short* __restrict__ out) {
    const float* src = blockIdx.y == 0 ? a0 : blockIdx.y == 1 ? a1 : a2;
    unsigned short* dst = out + (size_t)blockIdx.y * NE_;
    int i = (blockIdx.x * 256 + threadIdx.x) * 4;
    float4 v = *(const float4*)&src[i];
    ushort4 h;
    h.x = f2bf(v.x); h.y = f2bf(v.y); h.z = f2bf(v.z); h.w = f2bf(v.w);
    *(ushort4*)&dst[i] = h;
}

// ---------------- fused QKV projection ----------------
// grid (64, 24). blockIdx.y>>3 = range (0:Q 1:K 2:V), each range uses its own
// A tensor (actb + range*NE) and weight rows [range*1024, +1024) of Wcat.
// Q/K write bf16 [B,H,S,DH] (Q scaled by log2e/32); V writes bf16 [B,H,DH,S].
__global__ __launch_bounds__(256) void gemm_qkv(const unsigned short* __restrict__ actb,
                                                const unsigned short* __restrict__ Wcat,
                                                const float* __restrict__ bq,
                                                const float* __restrict__ bk,
                                                const float* __restrict__ bvv,
                                                unsigned short* __restrict__ Qp,
                                                unsigned short* __restrict__ Kp,
                                                unsigned short* __restrict__ VTp,
                                                float scq)
{
    constexpr int K = 1024, BK = 32;
    __shared__ unsigned short As[128 * BK];
    __shared__ unsigned short Bs[128 * BK];

    const int tid = threadIdx.x, lane = tid & 63, wid = tid >> 6;
    const int row0 = blockIdx.x * 128, col0 = blockIdx.y * 128;
    const int range = blockIdx.y >> 3;
    const unsigned short* A = actb + (size_t)range * NE_;
    const int wm = (wid >> 1) * 64, wn = (wid & 1) * 64;
    const int fr = lane & 15, fg = lane >> 4;

    f32x4 acc[4][4] = {};

    const int srow = wid * 16 + (lane >> 2);
    const int scol = (lane & 3) * 8;
    const size_t abase = (size_t)(row0 + srow) * K + scol;
    const size_t bbase = (size_t)(col0 + srow) * K + scol;
    unsigned short* lA0 = &As[srow * BK + scol];
    unsigned short* lA1 = &As[(srow + 64) * BK + scol];
    unsigned short* lB0 = &Bs[srow * BK + scol];
    unsigned short* lB1 = &Bs[(srow + 64) * BK + scol];

    for (int k0 = 0; k0 < K; k0 += BK) {
        gl_lds16(&A[abase + k0], lA0);
        gl_lds16(&A[abase + (size_t)64 * K + k0], lA1);
        gl_lds16(&Wcat[bbase + k0], lB0);
        gl_lds16(&Wcat[bbase + (size_t)64 * K + k0], lB1);
        __syncthreads();

        bf16x8 af[4], bfr[4];
        #pragma unroll
        for (int i = 0; i < 4; ++i) af[i] = *(const bf16x8*)&As[(wm + i * 16 + fr) * BK + fg * 8];
        #pragma unroll
        for (int i = 0; i < 4; ++i) bfr[i] = *(const bf16x8*)&Bs[(wn + i * 16 + fr) * BK + fg * 8];
        #pragma unroll
        for (int i = 0; i < 4; ++i)
            #pragma unroll
            for (int j = 0; j < 4; ++j)
                acc[i][j] = __builtin_amdgcn_mfma_f32_16x16x32_bf16(af[i], bfr[j], acc[i][j], 0, 0, 0);
        __syncthreads();
    }

    const float os = range == 0 ? scq : 1.0f;
    const float* bp = range == 0 ? bq : range == 1 ? bk : bvv;
    unsigned short* OP = range == 0 ? Qp : Kp;

    #pragma unroll
    for (int i = 0; i < 4; ++i) {
        #pragma unroll
        for (int j = 0; j < 4; ++j) {
            int colr = (col0 + wn + j * 16 + fr) & 1023;
            float bias = bp[colr];
            int h = colr >> 6, dh = colr & 63;
            if (range == 2) {
                int row = row0 + wm + i * 16 + fg * 4;
                int b = row >> 11, s = row & 2047;
                unsigned int w0 = f2bf(acc[i][j][0] + bias) | (f2bf(acc[i][j][1] + bias) << 16);
                unsigned int w1 = f2bf(acc[i][j][2] + bias) | (f2bf(acc[i][j][3] + bias) << 16);
                *(uint2*)&VTp[((size_t)((b << 4) + h) * 64 + dh) * 2048 + s] = make_uint2(w0, w1);
            } else {
                #pragma unroll
                for (int r = 0; r < 4; ++r) {
                    int row = row0 + wm + i * 16 + fg * 4 + r;
                    int b = row >> 11, s = row & 2047;
                    OP[((((b << 4) + h) * 2048 + s) << 6) + dh] =
                        (unsigned short)f2bf((acc[i][j][r] + bias) * os);
                }
            }
        }
    }
}

// ---------------- output projection: fp32 out = Ctx @ Wo^T + bo ----------------
__global__ __launch_bounds__(256) void gemm_o(const unsigned short* __restrict__ A,
                                              const unsigned short* __restrict__ Bw,
                                              const float* __restrict__ bias,
                                              float* __restrict__ Cf)
{
    constexpr int K = 1024, BK = 32, N = 1024;
    __shared__ unsigned short As[128 * BK];
    __shared__ unsigned short Bs[128 * BK];

    const int tid = threadIdx.x, lane = tid & 63, wid = tid >> 6;
    const int row0 = blockIdx.x * 128, col0 = blockIdx.y * 128;
    const int wm = (wid >> 1) * 64, wn = (wid & 1) * 64;
    const int fr = lane & 15, fg = lane >> 4;

    f32x4 acc[4][4] = {};

    const int srow = wid * 16 + (lane >> 2);
    const int scol = (lane & 3) * 8;
    const size_t abase = (size_t)(row0 + srow) * K + scol;
    const size_t bbase = (size_t)(col0 + srow) * K + scol;
    unsigned short* lA0 = &As[srow * BK + scol];
    unsigned short* lA1 = &As[(srow + 64) * BK + scol];
    unsigned short* lB0 = &Bs[srow * BK + scol];
    unsigned short* lB1 = &Bs[(srow + 64) * BK + scol];

    for (int k0 = 0; k0 < K; k0 += BK) {
        gl_lds16(&A[abase + k0], lA0);
        gl_lds16(&A[abase + (size_t)64 * K + k0], lA1);
        gl_lds16(&Bw[bbase + k0], lB0);
        gl_lds16(&Bw[bbase + (size_t)64 * K + k0], lB1);
        __syncthreads();

        bf16x8 af[4], bfr[4];
        #pragma unroll
        for (int i = 0; i < 4; ++i) af[i] = *(const bf16x8*)&As[(wm + i * 16 + fr) * BK + fg * 8];
        #pragma unroll
        for (int i = 0; i < 4; ++i) bfr[i] = *(const bf16x8*)&Bs[(wn + i * 16 + fr) * BK + fg * 8];
        #pragma unroll
        for (int i = 0; i < 4; ++i)
            #pragma unroll
            for (int j = 0; j < 4; ++j)
                acc[i][j] = __builtin_amdgcn_mfma_f32_16x16x32_bf16(af[i], bfr[j], acc[i][j], 0, 0, 0);
        __syncthreads();
    }

    #pragma unroll
    for (int i = 0; i < 4; ++i) {
        #pragma unroll
        for (int j = 0; j < 4; ++j) {
            int col = col0 + wn + j * 16 + fr;
            float bv = bias[col];
            #pragma unroll
            for (int r = 0; r < 4; ++r) {
                int row = row0 + wm + i * 16 + fg * 4 + r;
                Cf[(size_t)row * N + col] = acc[i][j][r] + bv;
            }
        }
    }
}

// ---------------- Flash attention v5 ----------------
// Grid 1024: lin -> xcd=lin&7, head=(lin>>3)&7, j=15-(lin>>6) (heavy first).
// 512 thr = 8 waves x 16 q-rows = 128-row q-tile, single j per block -> 4 blocks/CU.
// Swapped QK^T (S^T in regs), defer-max (THR=8), compiler cvt_pk P-pack.
__global__ __launch_bounds__(512, 4) void attn_fwd5(const unsigned short* __restrict__ Qp,
                                                    const unsigned short* __restrict__ Kp,
                                                    const unsigned short* __restrict__ VTg,
                                                    unsigned short* __restrict__ ctx)
{
    __shared__ unsigned short Ks[64][68];
    __shared__ unsigned short Vt[64][68];
    __shared__ unsigned short Ps[8][16][68];

    const int lin = blockIdx.x;
    const int xcd = lin & 7;
    const int w = lin >> 3;
    const int bh = xcd * 8 + (w & 7);     // XCD owns 8 complete heads
    const int j = 15 - (w >> 3);          // j=15 blocks first (32 tiles)
    const int b = bh >> 4, h = bh & 15;
    const int tid = threadIdx.x, lane = tid & 63, wid = tid >> 6;
    const int fr = lane & 15, fg = lane >> 4;

    const unsigned short* Qh  = Qp  + (size_t)bh * (S_ * DH_);
    const unsigned short* Kh  = Kp  + (size_t)bh * (S_ * DH_);
    const unsigned short* VTh = VTg + (size_t)bh * (DH_ * S_);

    const int srow = tid >> 3;
    const int scol = (tid & 7) * 8;

    bf16x8 ones;
    #pragma unroll
    for (int i = 0; i < 8; ++i) ones[i] = (__bf16)1.0f;

    const int q0 = j * 128;
    const int ntiles = 2 * (j + 1);
    const int rbase = q0 + wid * 16;
    const int qg = rbase + fr;            // this lane's q row

    bf16x8 qf[2];                         // B-frag: lane holds Q-row qg
    #pragma unroll
    for (int ks = 0; ks < 2; ++ks)
        qf[ks] = *(const bf16x8*)&Qh[(size_t)qg * 64 + ks * 32 + 8 * fg];

    f32x4 oacc[4] = {};                   // O^T: col q=fr, rows dh
    float m_run = -3.0e38f, l_run = 0.0f;

    int4 kreg = *(const int4*)&Kh[(size_t)srow * 64 + scol];
    int4 vreg = *(const int4*)&VTh[(size_t)srow * 2048 + scol];

    for (int kt = 0; kt < ntiles; ++kt) {
        const int kv0 = kt * 64;
        __syncthreads();
        *(int4*)&Ks[srow][scol] = kreg;
        *(int4*)&Vt[srow][scol] = vreg;
        if (kt + 1 < ntiles) {
            const int kv1 = kv0 + 64;
            kreg = *(const int4*)&Kh[(size_t)(kv1 + srow) * 64 + scol];
            vreg = *(const int4*)&VTh[(size_t)srow * 2048 + kv1 + scol];
        }
        __syncthreads();

        if (kv0 > rbase + 15) continue;   // wave fully masked for this tile

        // S^T = K @ Q^T : lane (fr,fg), reg r, tile nt = S[q=qg][kv0+nt*16+fg*4+r]
        f32x4 sacc[4] = {};
        #pragma unroll
        for (int nt = 0; nt < 4; ++nt)
            #pragma unroll
            for (int ks = 0; ks < 2; ++ks) {
                bf16x8 kf = *(const bf16x8*)&Ks[nt * 16 + fr][ks * 32 + 8 * fg];
                sacc[nt] = __builtin_amdgcn_mfma_f32_16x16x32_bf16(kf, qf[ks], sacc[nt], 0, 0, 0);
            }

        if (kv0 + 63 > rbase) {
            const int kbase = kv0 + fg * 4;
            #pragma unroll
            for (int nt = 0; nt < 4; ++nt)
                #pragma unroll
                for (int r = 0; r < 4; ++r)
                    if (kbase + nt * 16 + r > qg) sacc[nt][r] = -3.0e38f;
        }

        // per-q-row max: 15 in-lane fmax + 2 cross-fg shuffles
        float vm = sacc[0][0];
        #pragma unroll
        for (int nt = 0; nt < 4; ++nt)
            #pragma unroll
            for (int r = 0; r < 4; ++r) vm = fmaxf(vm, sacc[nt][r]);
        vm = fmaxf(vm, __shfl_xor(vm, 16));
        vm = fmaxf(vm, __shfl_xor(vm, 32));

        // defer-max: only rescale when some row exceeds m_run by > 8 (exp2 units)
        if (!__all(vm - m_run <= 8.0f)) {
            const float mn = fmaxf(m_run, vm);
            const float alpha = exp2f(m_run - mn);
            m_run = mn;
            l_run *= alpha;
            #pragma unroll
            for (int dt = 0; dt < 4; ++dt)
                #pragma unroll
                for (int r = 0; r < 4; ++r) oacc[dt][r] *= alpha;
        }

        // P = exp2(S - m) -> bf16 pack (compiler cvt_pk) -> wave-private LDS
        #pragma unroll
        for (int nt = 0; nt < 4; ++nt) {
            bf16x4 t;
            t[0] = (__bf16)exp2f(sacc[nt][0] - m_run);
            t[1] = (__bf16)exp2f(sacc[nt][1] - m_run);
            t[2] = (__bf16)exp2f(sacc[nt][2] - m_run);
            t[3] = (__bf16)exp2f(sacc[nt][3] - m_run);
            *(bf16x4*)&Ps[wid][fr][nt * 16 + fg * 4] = t;
        }
        asm volatile("s_waitcnt lgkmcnt(0)" ::: "memory");

        bf16x8 pb[2];                     // B-frag: lane holds P-row q=fr
        #pragma unroll
        for (int ks = 0; ks < 2; ++ks)
            pb[ks] = *(const bf16x8*)&Ps[wid][fr][ks * 32 + 8 * fg];

        f32x4 racc = {};
        #pragma unroll
        for (int ks = 0; ks < 2; ++ks)
            racc = __builtin_amdgcn_mfma_f32_16x16x32_bf16(ones, pb[ks], racc, 0, 0, 0);
        #pragma unroll
        for (int dt = 0; dt < 4; ++dt)
            #pragma unroll
            for (int ks = 0; ks < 2; ++ks) {
                bf16x8 vf = *(const bf16x8*)&Vt[dt * 16 + fr][ks * 32 + 8 * fg];
                oacc[dt] = __builtin_amdgcn_mfma_f32_16x16x32_bf16(vf, pb[ks], oacc[dt], 0, 0, 0);
            }
        l_run += racc[0];
    }

    // epilogue: lane's q = one s-row; 4 packed b64 stores
    const float linv = 1.0f / l_run;
    unsigned short* cb = &ctx[(size_t)(b * 2048 + qg) * 1024 + h * 64];
    #pragma unroll
    for (int dt = 0; dt < 4; ++dt) {
        unsigned int w0 = f2bf(oacc[dt][0] * linv) | (f2bf(oacc[dt][1] * linv) << 16);
        unsigned int w1 = f2bf(oacc[dt][2] * linv) | (f2bf(oacc[dt][3] * linv) << 16);
        *(uint2*)&cb[dt * 16 + fg * 4] = make_uint2(w0, w1);
    }
}

extern "C" void kernel_launch(void* const* d_in, const int* in_sizes, int n_in,
                              void* d_out, int out_size, void* d_ws, size_t ws_size,
                              hipStream_t stream)
{
    const float* q  = (const float*)d_in[0];
    const float* k  = (const float*)d_in[1];
    const float* v  = (const float*)d_in[2];
    const float* Wq = (const float*)d_in[4];
    const float* bq = (const float*)d_in[5];
    const float* Wk = (const float*)d_in[6];
    const float* bk = (const float*)d_in[7];
    const float* Wv = (const float*)d_in[8];
    const float* bv = (const float*)d_in[9];
    const float* Wo = (const float*)d_in[10];
    const float* bo = (const float*)d_in[11];
    float* out = (float*)d_out;

    unsigned short* Wcat = (unsigned short*)d_ws;          // [Wq;Wk;Wv;Wo] bf16
    unsigned short* actb = Wcat + 4 * 1048576;             // [qb;kb;vb]
    unsigned short* Qp   = actb + 3 * (size_t)NE_;
    unsigned short* Kp   = Qp + NE_;
    unsigned short* VTp  = Kp + NE_;                       // V in [B,H,DH,S]
    unsigned short* Ctx  = VTp + NE_;

    const float SCQ = 0.045084220027780106f;  // log2(e)/sqrt(D)

    dim3 blk(256);
    cvt_w4<<<dim3(1024, 4), blk, 0, stream>>>(Wq, Wk, Wv, Wo, Wcat);
    cvt_a3<<<dim3(8192, 3), blk, 0, stream>>>(q, k, v, actb);

    gemm_qkv<<<dim3(64, 24), blk, 0, stream>>>(actb, Wcat, bq, bk, bv, Qp, Kp, VTp, SCQ);

    attn_fwd5<<<dim3(1024), dim3(512), 0, stream>>>(Qp, Kp, VTp, Ctx);

    gemm_o<<<dim3(64, 8), blk, 0, stream>>>(Ctx, Wcat + 3 * 1048576, bo, out);
}